// Round 1
// baseline (1760.937 us; speedup 1.0000x reference)
//
#include <hip/hip_runtime.h>

// PerturbationModel: scores = counts @ log_mix^T (+ log comm bias), LSE over K, grand sum.
// G=3 S=10 N=5000 K=20 O=1000. counts 600 MB fp32 -> memory-bound, floor ~95 us.
//
// R1: __launch_bounds__(512,4) + acc[4][20] spilled (natural VGPR >128) -> 2.17 GB scratch.
// R2 (this version): K-SPLIT across lane halves. Lanes 0-31 compute k=0..9, lanes 32-63
// compute k=10..19 for the SAME 4 rows (same addresses -> memory system dedups; HBM traffic
// unchanged; LDS:HBM ratio unchanged at 5:1). acc[4][10]=40 VGPR instead of 80, plus
// double-buffered counts prefetch (16 more) -> est ~95 VGPR, safely under the 128 cap that
// (512,4) enforces. Restores 16 waves/CU (2 blocks x 8 waves; LDS 80928 B = exactly 2/CU)
// vs the ~8 waves/CU the (512,2) build ran at. Theory: kernel was latency-bound at
// 2 waves/SIMD with vmcnt draining each 128-o chunk (~1.9 TB/s); 4 waves/SIMD + prefetch
// should reach HBM-bound ~5+ TB/s.

#define EPSF 1e-6f
constexpr int Gc = 3, Sc = 10, Nc = 5000, Kc = 20, Oc = 1000;
constexpr int ROWS_PER_G = Sc * Nc;                  // 50000
constexpr int GRAN_ROWS  = 4;                        // rows per wave-granule (shared by both halves)
constexpr int GRANS_PER_G = ROWS_PER_G / GRAN_ROWS;  // 12500 (exact)
constexpr int KH = Kc / 2;                           // 10 k's per lane-half
constexpr int LM_ELEMS = Kc * Oc;                    // 20000
constexpr int LM_ALLOC = LM_ELEMS + 32;              // guard pad for tail-lane float4 reads

// 32-lane-group sum via DPP (VALU pipe only). Result valid in lanes 31 and 63.
__device__ __forceinline__ float red32(float v) {
  v += __int_as_float(__builtin_amdgcn_update_dpp(0, __float_as_int(v), 0x111, 0xF, 0xF, true)); // row_shr:1
  v += __int_as_float(__builtin_amdgcn_update_dpp(0, __float_as_int(v), 0x112, 0xF, 0xF, true)); // row_shr:2
  v += __int_as_float(__builtin_amdgcn_update_dpp(0, __float_as_int(v), 0x114, 0xF, 0xF, true)); // row_shr:4
  v += __int_as_float(__builtin_amdgcn_update_dpp(0, __float_as_int(v), 0x118, 0xF, 0xF, true)); // row_shr:8
  v += __int_as_float(__builtin_amdgcn_update_dpp(0, __float_as_int(v), 0x142, 0xF, 0xF, true)); // row_bcast:15
  return v;
}

__global__ __launch_bounds__(512, 4) void perturb_kernel(
    const float* __restrict__ counts, const float* __restrict__ otu,
    const float* __restrict__ comm,   const float* __restrict__ cw,
    const float* __restrict__ cc,     const float* __restrict__ gamma_p,
    float* __restrict__ out) {
  // LDS: 80128 + 800 = 80928 B -> exactly 2 blocks/CU (2 x 80928 <= 163840)
  __shared__ float s_lm[LM_ALLOC];     // [k][o] log(mix+eps) for this block's g
  __shared__ float s_bias[Sc * Kc];    // [s][k] log(comm+eps) for this g

  const int tid  = threadIdx.x;
  const int bid  = blockIdx.x;
  const int g    = bid % Gc;
  const int bg   = bid / Gc;
  const int blocksg = (gridDim.x + (Gc - 1) - g) / Gc;

  const float cwg = cw[g];
  const float gam = gamma_p[0];

  // ---- stage log_mix + bias into LDS ----
  for (int idx = tid; idx < LM_ALLOC; idx += blockDim.x) {
    float v = 0.f;
    if (idx < LM_ELEMS) {
      int o = idx % Oc;                 // idx = k*1000 + o, otu is [K][O] so otu[idx]
      float mix = otu[idx] * (1.f - cwg) + cwg * cc[g * Oc + o];
      v = __logf(mix + EPSF);
    }
    s_lm[idx] = v;
  }
  for (int idx = tid; idx < Sc * Kc; idx += blockDim.x) {
    int s = idx / Kc, k = idx - s * Kc;
    s_bias[idx] = __logf(comm[(k * Gc + g) * Sc + s] + EPSF);
  }
  __syncthreads();

  const int wave = tid >> 6;
  const int lane = tid & 63;
  const int rl   = lane >> 5;          // which k-half this lane computes
  const int osub = lane & 31;          // o-column group within 128-o chunk
  const int k0   = rl * KH;            // 0 or 10
  const int oc0  = osub << 2;

  const int waveg  = bg * 8 + wave;    // wave index among this g's waves
  const int nwaveg = blocksg * 8;

  float lsum = 0.f;                    // per-lane LSE accumulator (valid in lane 31)

  for (int gr = waveg; gr < GRANS_PER_G; gr += nwaveg) {
    const int row0 = gr * GRAN_ROWS;   // g-local first row; both halves cover rows row0..row0+3
    const float* base = counts + (size_t)(g * ROWS_PER_G + row0) * Oc;

    float acc[GRAN_ROWS][KH];
#pragma unroll
    for (int r = 0; r < GRAN_ROWS; ++r)
#pragma unroll
      for (int kk = 0; kk < KH; ++kk) acc[r][kk] = 0.f;

    // prologue: load chunk j=0 (o in [0,128), fully in-range)
    float4 c0 = *(const float4*)(base + 0 * Oc + oc0);
    float4 c1 = *(const float4*)(base + 1 * Oc + oc0);
    float4 c2 = *(const float4*)(base + 2 * Oc + oc0);
    float4 c3 = *(const float4*)(base + 3 * Oc + oc0);

    // 7 full 128-o chunks, each prefetching the next before computing (vmcnt never drains)
    for (int j = 0; j < 7; ++j) {
      const int obn = (j + 1) * 128 + oc0;
      float4 n0 = {0,0,0,0}, n1 = {0,0,0,0}, n2 = {0,0,0,0}, n3 = {0,0,0,0};
      if (j < 6 || osub < 26) {        // j=6 prefetches the tail chunk (26 active lanes)
        n0 = *(const float4*)(base + 0 * Oc + obn);
        n1 = *(const float4*)(base + 1 * Oc + obn);
        n2 = *(const float4*)(base + 2 * Oc + obn);
        n3 = *(const float4*)(base + 3 * Oc + obn);
      }
      const int ob = j * 128 + oc0;
      const float* lp = &s_lm[k0 * Oc + ob];
#pragma unroll
      for (int kk = 0; kk < KH; ++kk) {
        float4 L = *(const float4*)(lp + kk * Oc);
        acc[0][kk] += c0.x * L.x + c0.y * L.y + c0.z * L.z + c0.w * L.w;
        acc[1][kk] += c1.x * L.x + c1.y * L.y + c1.z * L.z + c1.w * L.w;
        acc[2][kk] += c2.x * L.x + c2.y * L.y + c2.z * L.z + c2.w * L.w;
        acc[3][kk] += c3.x * L.x + c3.y * L.y + c3.z * L.z + c3.w * L.w;
      }
      c0 = n0; c1 = n1; c2 = n2; c3 = n3;
    }
    // tail compute: o in [896,1000). c regs hold the masked tail loads (zeros beyond o=1000).
    {
      const int ob = 896 + oc0;
      const float* lp = &s_lm[k0 * Oc + ob];   // guard pad covers o >= 1000 (c is 0 there)
#pragma unroll
      for (int kk = 0; kk < KH; ++kk) {
        float4 L = *(const float4*)(lp + kk * Oc);
        acc[0][kk] += c0.x * L.x + c0.y * L.y + c0.z * L.z + c0.w * L.w;
        acc[1][kk] += c1.x * L.x + c1.y * L.y + c1.z * L.z + c1.w * L.w;
        acc[2][kk] += c2.x * L.x + c2.y * L.y + c2.z * L.z + c2.w * L.w;
        acc[3][kk] += c3.x * L.x + c3.y * L.y + c3.z * L.z + c3.w * L.w;
      }
    }

    // reduce each acc over the 32 o-lanes (DPP, VALU pipe). lanes 31/63 hold half-sums.
#pragma unroll
    for (int r = 0; r < GRAN_ROWS; ++r)
#pragma unroll
      for (int kk = 0; kk < KH; ++kk) acc[r][kk] = red32(acc[r][kk]);

    if ((lane & 31) == 31) {           // lanes 31 (k=0..9) and 63 (k=10..19) active
#pragma unroll
      for (int r = 0; r < GRAN_ROWS; ++r) {
        const int s = (row0 + r) / Nc;
        const float* bp = &s_bias[s * Kc + k0];
        float x[KH];
        float m = -3.4e38f;
#pragma unroll
        for (int kk = 0; kk < KH; ++kk) {
          x[kk] = acc[r][kk] + bp[kk];
          m = fmaxf(m, x[kk]);
        }
        // combine the two k-halves: lane31 <-> lane63
        const float mo = __shfl_xor(m, 32);
        const float mm = fmaxf(m, mo);
        float ssum = 0.f;
#pragma unroll
        for (int kk = 0; kk < KH; ++kk) ssum += __expf(gam * (x[kk] - mm));
        const float so = __shfl_xor(ssum, 32);
        if (rl == 0) lsum += mm + __logf(ssum + so);
      }
    }
  }

  if (lane == 31) atomicAdd(out, lsum);
}

extern "C" void kernel_launch(void* const* d_in, const int* in_sizes, int n_in,
                              void* d_out, int out_size, void* d_ws, size_t ws_size,
                              hipStream_t stream) {
  const float* counts = (const float*)d_in[0];
  const float* otu    = (const float*)d_in[1];
  const float* comm   = (const float*)d_in[2];
  const float* cw     = (const float*)d_in[3];
  const float* cc     = (const float*)d_in[4];
  const float* gam    = (const float*)d_in[5];
  float* out = (float*)d_out;

  hipMemsetAsync(out, 0, sizeof(float), stream);
  hipLaunchKernelGGL(perturb_kernel, dim3(512), dim3(512), 0, stream,
                     counts, otu, comm, cw, cc, gam, out);
}

// Round 2
// 1252.113 us; speedup vs baseline: 1.4064x; 1.4064x over previous
//
#include <hip/hip_runtime.h>

// PerturbationModel: scores = counts @ log_mix^T (+ log comm bias), LSE over K, grand sum.
// G=3 S=10 N=5000 K=20 O=1000. counts 600 MB fp32 -> memory-bound, floor ~95 us.
//
// R1: (512,4)+acc[4][20] spilled. R2: K-split+prefetch with (512,4) ALSO spilled:
//   VGPR_Count=64 + 988 MB WRITE_SIZE proves launch_bounds arg2 is CUDA-style
//   min-BLOCKS-per-CU on this toolchain: (512,4)=32 waves/CU -> 64-VGPR cap.
// R3 (this version): same K-split + prefetch structure, but __launch_bounds__(512,2)
//   -> 16 waves/CU -> 128-VGPR cap. Natural usage ~100 (acc[4][10]=40 + cur/next
//   float4 quads 32 + addressing) fits. LDS 80928 B still = 2 blocks/CU.
// Theory: R0 (290 us) was MLP-limited -- vmcnt drained to 0 every 128-o chunk, avg
//   in-flight ~15 KB/CU < ~20 KB needed for 6.3 TB/s at loaded latency. Register
//   prefetch keeps 4 loads in flight through each compute phase -> ~32 KB/CU ->
//   HBM-saturated. Predict kernel ~110-180 us, FETCH ~0.63 GB, WRITE ~0 GB.

#define EPSF 1e-6f
constexpr int Gc = 3, Sc = 10, Nc = 5000, Kc = 20, Oc = 1000;
constexpr int ROWS_PER_G = Sc * Nc;                  // 50000
constexpr int GRAN_ROWS  = 4;                        // rows per wave-granule (shared by both lane halves)
constexpr int GRANS_PER_G = ROWS_PER_G / GRAN_ROWS;  // 12500 (exact)
constexpr int KH = Kc / 2;                           // 10 k's per lane-half
constexpr int LM_ELEMS = Kc * Oc;                    // 20000
constexpr int LM_ALLOC = LM_ELEMS + 32;              // guard pad for tail-lane float4 reads

// 32-lane-group sum via DPP (VALU pipe only). Result valid in lanes 31 and 63.
__device__ __forceinline__ float red32(float v) {
  v += __int_as_float(__builtin_amdgcn_update_dpp(0, __float_as_int(v), 0x111, 0xF, 0xF, true)); // row_shr:1
  v += __int_as_float(__builtin_amdgcn_update_dpp(0, __float_as_int(v), 0x112, 0xF, 0xF, true)); // row_shr:2
  v += __int_as_float(__builtin_amdgcn_update_dpp(0, __float_as_int(v), 0x114, 0xF, 0xF, true)); // row_shr:4
  v += __int_as_float(__builtin_amdgcn_update_dpp(0, __float_as_int(v), 0x118, 0xF, 0xF, true)); // row_shr:8
  v += __int_as_float(__builtin_amdgcn_update_dpp(0, __float_as_int(v), 0x142, 0xF, 0xF, true)); // row_bcast:15
  return v;
}

__global__ __launch_bounds__(512, 2) void perturb_kernel(
    const float* __restrict__ counts, const float* __restrict__ otu,
    const float* __restrict__ comm,   const float* __restrict__ cw,
    const float* __restrict__ cc,     const float* __restrict__ gamma_p,
    float* __restrict__ out) {
  // LDS: 80128 + 800 = 80928 B -> exactly 2 blocks/CU (2 x 80928 <= 163840)
  __shared__ float s_lm[LM_ALLOC];     // [k][o] log(mix+eps) for this block's g
  __shared__ float s_bias[Sc * Kc];    // [s][k] log(comm+eps) for this g

  const int tid  = threadIdx.x;
  const int bid  = blockIdx.x;
  const int g    = bid % Gc;
  const int bg   = bid / Gc;
  const int blocksg = (gridDim.x + (Gc - 1) - g) / Gc;

  const float cwg = cw[g];
  const float gam = gamma_p[0];

  // ---- stage log_mix + bias into LDS ----
  for (int idx = tid; idx < LM_ALLOC; idx += blockDim.x) {
    float v = 0.f;
    if (idx < LM_ELEMS) {
      int o = idx % Oc;                 // idx = k*1000 + o, otu is [K][O] so otu[idx]
      float mix = otu[idx] * (1.f - cwg) + cwg * cc[g * Oc + o];
      v = __logf(mix + EPSF);
    }
    s_lm[idx] = v;
  }
  for (int idx = tid; idx < Sc * Kc; idx += blockDim.x) {
    int s = idx / Kc, k = idx - s * Kc;
    s_bias[idx] = __logf(comm[(k * Gc + g) * Sc + s] + EPSF);
  }
  __syncthreads();

  const int wave = tid >> 6;
  const int lane = tid & 63;
  const int rl   = lane >> 5;          // which k-half this lane computes
  const int osub = lane & 31;          // o-column group within 128-o chunk
  const int k0   = rl * KH;            // 0 or 10
  const int oc0  = osub << 2;

  const int waveg  = bg * 8 + wave;    // wave index among this g's waves
  const int nwaveg = blocksg * 8;

  float lsum = 0.f;                    // per-lane LSE accumulator (valid in lane 31, rl==0)

  for (int gr = waveg; gr < GRANS_PER_G; gr += nwaveg) {
    const int row0 = gr * GRAN_ROWS;   // g-local first row; both halves cover rows row0..row0+3
    const float* base = counts + (size_t)(g * ROWS_PER_G + row0) * Oc;

    float acc[GRAN_ROWS][KH];
#pragma unroll
    for (int r = 0; r < GRAN_ROWS; ++r)
#pragma unroll
      for (int kk = 0; kk < KH; ++kk) acc[r][kk] = 0.f;

    // prologue: load chunk j=0 (o in [0,128), fully in-range)
    float4 c0 = *(const float4*)(base + 0 * Oc + oc0);
    float4 c1 = *(const float4*)(base + 1 * Oc + oc0);
    float4 c2 = *(const float4*)(base + 2 * Oc + oc0);
    float4 c3 = *(const float4*)(base + 3 * Oc + oc0);

    // 7 full 128-o chunks, each prefetching the next before computing
    // (4 loads stay in flight across every compute phase -> MLP)
    for (int j = 0; j < 7; ++j) {
      const int obn = (j + 1) * 128 + oc0;
      float4 n0 = {0,0,0,0}, n1 = {0,0,0,0}, n2 = {0,0,0,0}, n3 = {0,0,0,0};
      if (j < 6 || osub < 26) {        // j=6 prefetches the tail chunk (26 active float4 lanes)
        n0 = *(const float4*)(base + 0 * Oc + obn);
        n1 = *(const float4*)(base + 1 * Oc + obn);
        n2 = *(const float4*)(base + 2 * Oc + obn);
        n3 = *(const float4*)(base + 3 * Oc + obn);
      }
      const int ob = j * 128 + oc0;
      const float* lp = &s_lm[k0 * Oc + ob];
#pragma unroll
      for (int kk = 0; kk < KH; ++kk) {
        float4 L = *(const float4*)(lp + kk * Oc);
        acc[0][kk] += c0.x * L.x + c0.y * L.y + c0.z * L.z + c0.w * L.w;
        acc[1][kk] += c1.x * L.x + c1.y * L.y + c1.z * L.z + c1.w * L.w;
        acc[2][kk] += c2.x * L.x + c2.y * L.y + c2.z * L.z + c2.w * L.w;
        acc[3][kk] += c3.x * L.x + c3.y * L.y + c3.z * L.z + c3.w * L.w;
      }
      c0 = n0; c1 = n1; c2 = n2; c3 = n3;
    }
    // tail compute: o in [896,1000). c regs hold the masked tail loads (zeros beyond o=1000,
    // so the s_lm values read there -- next k's row / guard pad -- are multiplied by 0).
    {
      const int ob = 896 + oc0;
      const float* lp = &s_lm[k0 * Oc + ob];
#pragma unroll
      for (int kk = 0; kk < KH; ++kk) {
        float4 L = *(const float4*)(lp + kk * Oc);
        acc[0][kk] += c0.x * L.x + c0.y * L.y + c0.z * L.z + c0.w * L.w;
        acc[1][kk] += c1.x * L.x + c1.y * L.y + c1.z * L.z + c1.w * L.w;
        acc[2][kk] += c2.x * L.x + c2.y * L.y + c2.z * L.z + c2.w * L.w;
        acc[3][kk] += c3.x * L.x + c3.y * L.y + c3.z * L.z + c3.w * L.w;
      }
    }

    // reduce each acc over the 32 o-lanes (DPP, VALU pipe). lanes 31/63 hold half-sums.
#pragma unroll
    for (int r = 0; r < GRAN_ROWS; ++r)
#pragma unroll
      for (int kk = 0; kk < KH; ++kk) acc[r][kk] = red32(acc[r][kk]);

    if ((lane & 31) == 31) {           // lanes 31 (k=0..9) and 63 (k=10..19) active
#pragma unroll
      for (int r = 0; r < GRAN_ROWS; ++r) {
        const int s = (row0 + r) / Nc;
        const float* bp = &s_bias[s * Kc + k0];
        float m = -3.4e38f;
#pragma unroll
        for (int kk = 0; kk < KH; ++kk) {
          acc[r][kk] += bp[kk];        // reuse acc in place (no extra x[] regs)
          m = fmaxf(m, acc[r][kk]);
        }
        // combine the two k-halves: lane31 <-> lane63
        const float mo = __shfl_xor(m, 32);
        const float mm = fmaxf(m, mo);
        float ssum = 0.f;
#pragma unroll
        for (int kk = 0; kk < KH; ++kk) ssum += __expf(gam * (acc[r][kk] - mm));
        const float so = __shfl_xor(ssum, 32);
        if (rl == 0) lsum += mm + __logf(ssum + so);
      }
    }
  }

  if (lane == 31) atomicAdd(out, lsum);
}

extern "C" void kernel_launch(void* const* d_in, const int* in_sizes, int n_in,
                              void* d_out, int out_size, void* d_ws, size_t ws_size,
                              hipStream_t stream) {
  const float* counts = (const float*)d_in[0];
  const float* otu    = (const float*)d_in[1];
  const float* comm   = (const float*)d_in[2];
  const float* cw     = (const float*)d_in[3];
  const float* cc     = (const float*)d_in[4];
  const float* gam    = (const float*)d_in[5];
  float* out = (float*)d_out;

  hipMemsetAsync(out, 0, sizeof(float), stream);
  hipLaunchKernelGGL(perturb_kernel, dim3(512), dim3(512), 0, stream,
                     counts, otu, comm, cw, cc, gam, out);
}